// Round 10
// baseline (928.847 us; speedup 1.0000x reference)
//
#include <hip/hip_runtime.h>
#include <stdint.h>

// ============================================================================
// CrossMultiHeadAttention (L=1024, N=8, E=1024, H=8) — round 10.
//
//  k_fsc v7 (= v6 + issue-timing fixes):
//   - stage B(t+2) moved BEFORE tile t's MFMA, guarded by lgkmcnt(0) (tile-t
//     ds_reads retired before the wave-private buffer can be overwritten).
//     MFMA now covers the stage issue -> lookahead ~2 tiles.
//   - A(2j+4),A(2j+5) stages moved into tile 2j+1's body (off the barrier
//     path). FIFO proofs: A's issued after B(2j+3), before B(2j+4); window-end
//     vmcnt(16) still drains A(2j+2),A(2j+3) (older than B(2j+2)); tile-wait
//     vmcnt(8) unchanged.
//  k_gemm256_out: custom decode pid%8 = (bx,z) -> each XCD's 2MB F panel is
//  L2-resident for the final split-K GEMM.
//  Everything else identical to round 9 (passing).
// ============================================================================

typedef unsigned short u16;
typedef unsigned int u32;
typedef __attribute__((ext_vector_type(8))) __bf16 bf16x8;
typedef __attribute__((ext_vector_type(4))) float f32x4;
typedef __attribute__((ext_vector_type(4))) u16 u16x4;

#define DEVFN static __device__ __forceinline__

static constexpr int LQ = 1024, NN = 8, EE = 1024, HH = 8, SS = 1024;
static constexpr long LNE = (long)LQ * NN * EE;   // 8,388,608
static constexpr long MM = 1048576;

// ws offsets (u16 elems)
static constexpr long OF_QBF   = 0;
static constexpr long OF_KBF   = 8388608;
static constexpr long OF_VALT  = 16777216;
static constexpr long OF_F     = 25165824;   // WqT first, later F
static constexpr long OF_WKT   = 33554432;
static constexpr long OF_WVT   = 41943040;
static constexpr long OF_WOT   = 50331648;
static constexpr long OF_WOUTB = 58720256;
static constexpr long OF_GT    = 67108864;
static constexpr long OF_BM    = 75497472;
static constexpr long OF_T     = 83886080;   // 67M u16: T, later U
static constexpr long OF_P     = 150994944;  // 67M u16: P, later 2 f32 partials
static constexpr long OF_SMALL_F = 109051904; // float index

DEVFN u16 f2bf(float x) {
  u32 u = __builtin_bit_cast(u32, x);
  u = (u + 0x7FFFu + ((u >> 16) & 1u)) >> 16;
  return (u16)u;
}
DEVFN float bf2f(u16 x) { return __builtin_bit_cast(float, (u32)x << 16); }

DEVFN void gload16(const u16* g, u16* l) {
  __builtin_amdgcn_global_load_lds(
      (const __attribute__((address_space(1))) void*)(uintptr_t)g,
      (__attribute__((address_space(3))) void*)(uintptr_t)l, 16, 0, 0);
}

#define BAR() asm volatile("s_barrier" ::: "memory")
#define VMCNT2() asm volatile("s_waitcnt vmcnt(2)" ::: "memory")
#define VMCNT0() asm volatile("s_waitcnt vmcnt(0)" ::: "memory")
#define VMCNT8() asm volatile("s_waitcnt vmcnt(8)" ::: "memory")
#define VMCNT16() asm volatile("s_waitcnt vmcnt(16)" ::: "memory")
#define LGKM0() asm volatile("s_waitcnt lgkmcnt(0)" ::: "memory")
#define SB0() __builtin_amdgcn_sched_barrier(0)

// ---------------- converts ----------------
struct Cvt3P { const float* s[3]; u16* d[3]; };
__global__ __launch_bounds__(256) void k_cvt3(Cvt3P p) {
  const int z = blockIdx.y;
  const float* s = p.s[z];
  u16* d = p.d[z];
  long i = (long)blockIdx.x * 256 + threadIdx.x;
  for (; i < 2097152; i += 131072) {
    float4 v = reinterpret_cast<const float4*>(s)[i];
    u16x4 o;
    o.x = f2bf(v.x); o.y = f2bf(v.y); o.z = f2bf(v.z); o.w = f2bf(v.w);
    reinterpret_cast<u16x4*>(d)[i] = o;
  }
}

struct Tp5P { const float* s[5]; u16* d[5]; int sld[5]; long szs[5]; long dzs[5]; };
__global__ __launch_bounds__(256) void k_tp5(Tp5P p) {
  const int cfg = blockIdx.z >> 3, zz = blockIdx.z & 7;
  const float* src = p.s[cfg] + (long)zz * p.szs[cfg];
  u16* dst = p.d[cfg] + (long)zz * p.dzs[cfg];
  const int sld = p.sld[cfg];
  __shared__ float t[64][65];
  const int r = threadIdx.x >> 4, c4 = (threadIdx.x & 15) * 4;
#pragma unroll
  for (int rr = 0; rr < 64; rr += 16) {
    float4 v = *reinterpret_cast<const float4*>(
        &src[(long)(blockIdx.y * 64 + r + rr) * sld + blockIdx.x * 64 + c4]);
    t[r + rr][c4] = v.x; t[r + rr][c4 + 1] = v.y;
    t[r + rr][c4 + 2] = v.z; t[r + rr][c4 + 3] = v.w;
  }
  __syncthreads();
#pragma unroll
  for (int rr = 0; rr < 64; rr += 16) {
    u16x4 o;
    o.x = f2bf(t[c4][r + rr]);     o.y = f2bf(t[c4 + 1][r + rr]);
    o.z = f2bf(t[c4 + 2][r + rr]); o.w = f2bf(t[c4 + 3][r + rr]);
    *reinterpret_cast<u16x4*>(
        &dst[(long)(blockIdx.x * 64 + r + rr) * 1024 + blockIdx.y * 64 + c4]) = o;
  }
}

// ---------------- beta vector: bvec_h[e] = sum_d Wk[h][d][e]*bq[h][d] -------
__global__ __launch_bounds__(256) void k_bvec(const float* __restrict__ Wqkv,
                                              const float* __restrict__ bqkv,
                                              float* __restrict__ bp) {
  const int ec = blockIdx.x, h = blockIdx.y, dc = blockIdx.z, t = threadIdx.x;
  const int e = ec * 256 + t;
  const float* wk = Wqkv + (long)h * 3145728 + 1048576;
  const float* bq = bqkv + h * 3072;
  float sb = 0.f;
  for (int dd = 0; dd < 128; ++dd) {
    const int d = dc * 128 + dd;
    sb += wk[(long)d * 1024 + e] * bq[d];
  }
  bp[dc * 8192 + h * 1024 + e] = sb;
}
__global__ __launch_bounds__(256) void k_redb(const float* __restrict__ bp,
                                              float* __restrict__ b) {
  const int i = blockIdx.x * 256 + threadIdx.x;
  float sb = 0.f;
#pragma unroll
  for (int dc = 0; dc < 8; ++dc) sb += bp[dc * 8192 + i];
  b[i] = sb;
}

// ---------------- beta[h,n,s] = key_row(s,n) · bvec_h -----------------------
__global__ __launch_bounds__(256) void k_rowdot(const float* __restrict__ X,
                                                const float* __restrict__ V,
                                                float* __restrict__ OUT) {
  const int wave = threadIdx.x >> 6, lane = threadIdx.x & 63;
  const int r = blockIdx.x * 4 + wave;  // row (s*8+n)
  const float4* xr = reinterpret_cast<const float4*>(X + (long)r * 1024);
  float acc[8];
#pragma unroll
  for (int h = 0; h < 8; ++h) acc[h] = 0.f;
#pragma unroll
  for (int it = 0; it < 4; ++it) {
    float4 q = xr[it * 64 + lane];
#pragma unroll
    for (int h = 0; h < 8; ++h) {
      float4 av = reinterpret_cast<const float4*>(V + h * 1024)[it * 64 + lane];
      acc[h] += q.x * av.x + q.y * av.y + q.z * av.z + q.w * av.w;
    }
  }
#pragma unroll
  for (int h = 0; h < 8; ++h)
#pragma unroll
    for (int o = 1; o < 64; o <<= 1) acc[h] += __shfl_xor(acc[h], o);
  if (lane == 0) {
    const int idx = r >> 3, n = r & 7;
#pragma unroll
    for (int h = 0; h < 8; ++h) OUT[h * 8192 + n * 1024 + idx] = acc[h];
  }
}

// ---------------- be2[e] = bout + Wout[e,:]·bo + Bm[e,:]·bv -----------------
__global__ __launch_bounds__(256) void k_be2(const float* __restrict__ Wout,
                                             const float* __restrict__ bo,
                                             const float* __restrict__ bout,
                                             const float* __restrict__ bqkv,
                                             const u16* __restrict__ Bm,
                                             float* __restrict__ be2) {
  const int e = blockIdx.x, t = threadIdx.x;
  float s = 0.f;
  for (int i = t; i < 8192; i += 256) {
    s += Wout[(long)e * 8192 + i] * bo[i];
    const int h = i >> 10, d = i & 1023;
    s += bf2f(Bm[(long)e * 8192 + i]) * bqkv[h * 3072 + 2048 + d];
  }
#pragma unroll
  for (int o = 1; o < 64; o <<= 1) s += __shfl_xor(s, o);
  __shared__ float ps[4];
  if ((t & 63) == 0) ps[t >> 6] = s;
  __syncthreads();
  if (t == 0) be2[e] = bout[e] + ps[0] + ps[1] + ps[2] + ps[3];
}

// ---------------- out = p0 + p1 + be2 ---------------------------------------
__global__ __launch_bounds__(256) void k_combine(const float* __restrict__ p0,
                                                 const float* __restrict__ p1,
                                                 const float* __restrict__ be,
                                                 float* __restrict__ out) {
  long i = (long)blockIdx.x * 256 + threadIdx.x;
  const long st = (long)gridDim.x * 256;
  for (; i < 2097152; i += st) {
    float4 a = reinterpret_cast<const float4*>(p0)[i];
    float4 b = reinterpret_cast<const float4*>(p1)[i];
    float4 c = reinterpret_cast<const float4*>(be)[i & 255];
    float4 o = {a.x + b.x + c.x, a.y + b.y + c.y, a.z + b.z + c.z, a.w + b.w + c.w};
    reinterpret_cast<float4*>(out)[i] = o;
  }
}

// ---------------- generic 256x256 8-phase B^T GEMM --------------------------
struct GemmP {
  const u16* A; const u16* B;
  float* Cf; u16* Cb;
  int lda, ldb, ldc, K, NB;
  long sAh, sAn, sBh, sBn, sCh, sCn;
  float scale;
};
struct GemmP2 { GemmP p0, p1; int split; };

template <int M0, int N0>
DEVFN void quad(f32x4 (&acc)[8][4], bf16x8 (&a)[4][2], bf16x8 (&b)[4][2]) {
#pragma unroll
  for (int mi = 0; mi < 4; ++mi)
#pragma unroll
    for (int ni = 0; ni < 2; ++ni) {
      acc[M0 + mi][N0 + ni] = __builtin_amdgcn_mfma_f32_16x16x32_bf16(
          a[mi][0], b[N0 + ni][0], acc[M0 + mi][N0 + ni], 0, 0, 0);
      acc[M0 + mi][N0 + ni] = __builtin_amdgcn_mfma_f32_16x16x32_bf16(
          a[mi][1], b[N0 + ni][1], acc[M0 + mi][N0 + ni], 0, 0, 0);
    }
}

DEVFN void swz_block(int& bx, int& by, int& bz) {
  long lid = blockIdx.x + (long)gridDim.x * (blockIdx.y + (long)gridDim.y * blockIdx.z);
  const long nwg = (long)gridDim.x * gridDim.y * gridDim.z;
  long s = (nwg % 8 == 0) ? ((lid % 8) * (nwg / 8) + lid / 8) : lid;
  bx = (int)(s % gridDim.x);
  long r2 = s / gridDim.x;
  by = (int)(r2 % gridDim.y);
  bz = (int)(r2 / gridDim.y);
}

template <int OUT_F32>
DEVFN void gemm_body(const GemmP& p, int bx, int by, int bz) {
  const int h = bz / p.NB, n = bz % p.NB;
  const u16* Ab = p.A + (long)h * p.sAh + (long)n * p.sAn;
  const u16* Bb = p.B + (long)h * p.sBh + (long)n * p.sBn;
  const long coff = (long)h * p.sCh + (long)n * p.sCn;
  const int row0 = by * 256;
  const int col0 = bx * 256;

  __shared__ u16 LDSU[65536];  // 128 KiB

  const int tid = threadIdx.x;
  const int wave = tid >> 6, lane = tid & 63;
  const int wr = wave >> 2, wc = wave & 3;
  const int NT = p.K >> 6;

  f32x4 acc[8][4];
  const f32x4 zero = {0.f, 0.f, 0.f, 0.f};
#pragma unroll
  for (int i = 0; i < 8; ++i)
#pragma unroll
    for (int j = 0; j < 4; ++j) acc[i][j] = zero;

  const int swc = ((lane & 7) ^ ((lane >> 3) & 7)) * 8;
  const u16* Ag = Ab + (long)(row0 + wave * 16 + (lane >> 3)) * p.lda + swc;
  const u16* Bg = Bb + (long)(col0 + wave * 16 + (lane >> 3)) * p.ldb + swc;

  auto STAGE = [&](int hh) {
    const int kt = hh >> 2;
    if (kt < NT) {
      const int pt = hh & 3;
      const int hf = pt >> 1;
      u16* l = &LDSU[((pt & 1) ? 32768 : 0) + (kt & 1) * 16384 + hf * 8192 + wave * 1024];
      const int ld = (pt & 1) ? p.ldb : p.lda;
      const u16* g = ((pt & 1) ? Bg : Ag) + (long)hf * 128 * ld + kt * 64;
      gload16(g, l);
      gload16(g + 8L * ld, l + 512);
    }
  };

  STAGE(0); STAGE(1); STAGE(2); STAGE(3); STAGE(4);
  VMCNT2();
  BAR();

  const int rA = lane & 15;
  const int c0 = (((lane >> 4)) ^ (lane & 7)) * 8;
  const int c1 = ((4 + (lane >> 4)) ^ (lane & 7)) * 8;

  bf16x8 a[4][2], b[4][2];

  for (int t = 0; t < NT; ++t) {
    const int db = (t & 1) * 16384;
    const u16* Ar = &LDSU[db + wr * 8192 + rA * 64];
    const u16* Br = &LDSU[32768 + db + (wc >> 1) * 8192 + ((wc & 1) * 64 + rA) * 64];

#pragma unroll
    for (int mi = 0; mi < 4; ++mi) {
      a[mi][0] = *reinterpret_cast<const bf16x8*>(&Ar[mi * 1024 + c0]);
      a[mi][1] = *reinterpret_cast<const bf16x8*>(&Ar[mi * 1024 + c1]);
    }
#pragma unroll
    for (int ni = 0; ni < 2; ++ni) {
      b[ni][0] = *reinterpret_cast<const bf16x8*>(&Br[ni * 1024 + c0]);
      b[ni][1] = *reinterpret_cast<const bf16x8*>(&Br[ni * 1024 + c1]);
    }
    STAGE(4 * t + 5);
    BAR();
    SB0(); __builtin_amdgcn_s_setprio(1);
    quad<0, 0>(acc, a, b);
    __builtin_amdgcn_s_setprio(0); SB0();
    BAR();

#pragma unroll
    for (int ni = 2; ni < 4; ++ni) {
      b[ni][0] = *reinterpret_cast<const bf16x8*>(&Br[ni * 1024 + c0]);
      b[ni][1] = *reinterpret_cast<const bf16x8*>(&Br[ni * 1024 + c1]);
    }
    STAGE(4 * t + 6);
    BAR();
    SB0(); __builtin_amdgcn_s_setprio(1);
    quad<0, 2>(acc, a, b);
    __builtin_amdgcn_s_setprio(0); SB0();
    BAR();

#pragma unroll
    for (int mi = 0; mi < 4; ++mi) {
      a[mi][0] = *reinterpret_cast<const bf16x8*>(&Ar[(4 + mi) * 1024 + c0]);
      a[mi][1] = *reinterpret_cast<const bf16x8*>(&Ar[(4 + mi) * 1024 + c1]);
    }
    STAGE(4 * t + 7);
    BAR();
    SB0(); __builtin_amdgcn_s_setprio(1);
    quad<4, 0>(acc, a, b);
    __builtin_amdgcn_s_setprio(0); SB0();
    BAR();

    STAGE(4 * t + 8);
    if (t < NT - 2) { VMCNT2(); }
    else if (t == NT - 2) { VMCNT0(); }
    BAR();
    SB0(); __builtin_amdgcn_s_setprio(1);
    quad<4, 2>(acc, a, b);
    __builtin_amdgcn_s_setprio(0); SB0();
    BAR();
  }

  const int crow = (lane >> 4) * 4;
  const int ccol = lane & 15;
#pragma unroll
  for (int mi = 0; mi < 8; ++mi) {
#pragma unroll
    for (int j = 0; j < 4; ++j) {
      const int grow = row0 + wr * 128 + mi * 16 + crow + j;
#pragma unroll
      for (int ni = 0; ni < 4; ++ni) {
        const int gcol = col0 + wc * 64 + ni * 16 + ccol;
        float v = acc[mi][ni][j] * p.scale;
        if constexpr (OUT_F32)
          p.Cf[coff + (long)grow * p.ldc + gcol] = v;
        else
          p.Cb[coff + (long)grow * p.ldc + gcol] = f2bf(v);
      }
    }
  }
}

template <int OUT_F32>
__global__ __launch_bounds__(512, 2) void k_gemm256(GemmP p) {
  int bx, by, bz;
  swz_block(bx, by, bz);
  gemm_body<OUT_F32>(p, bx, by, bz);
}
template <int OUT_F32>
__global__ __launch_bounds__(512, 2) void k_gemm256_pair(GemmP2 pp) {
  int bx, by, bz;
  swz_block(bx, by, bz);
  if (bz < pp.split) gemm_body<OUT_F32>(pp.p0, bx, by, bz);
  else gemm_body<OUT_F32>(pp.p1, bx, by, bz - pp.split);
}
// out GEMM: flat grid(256); pid%8 encodes (bx,z) -> 2MB F panel per XCD (L2).
template <int OUT_F32>
__global__ __launch_bounds__(512, 2) void k_gemm256_out(GemmP p) {
  const int pid = blockIdx.x;
  const int bx = pid & 3;
  const int bz = (pid >> 2) & 1;
  const int by = pid >> 3;
  gemm_body<OUT_F32>(p, bx, by, bz);
}

// ---------------- FUSED scores+softmax v7 (k_fsc) ---------------------------
struct FscP {
  const u16* T; const u16* K; const float* beta;
  float* attn; u16* P;
};
__global__ __launch_bounds__(512, 2) void k_fsc(FscP p) {
  const int lid = blockIdx.x + 16 * blockIdx.y;  // grid (16,64) -> 1024
  const int n = lid & 7;                          // XCD-local batch
  const int rest = lid >> 3;                      // 0..127
  const int bx = rest & 15;
  const int h = rest >> 4;
  const int row0 = bx * 64;

  __shared__ u16 BW[65536];   // 128 KB: w*8192 + buf*4096 + c*32 + pk*8
  __shared__ u16 AT[12288];   // 24 KB: slot*2048 + r*32 + pk*8  (slot = t%6)

  const int tid = threadIdx.x;
  const int w = tid >> 6, lane = tid & 63;
  const int rl = lane & 15, g4 = lane >> 4;

  const u16* Abase = p.T + (long)h * 8388608 + n * 1024 + (long)row0 * 8192;
  const int ksw = ((lane & 3) ^ ((lane >> 3) & 3)) * 8;
  const u16* Ag2 = Abase + (long)(lane >> 2) * 8192 + ksw;             // row
  const u16* Bg2 = p.K + n * 1024 + (long)(w * 128 + (lane >> 2)) * 8192 + ksw;

  f32x4 acc[4][8];
  const f32x4 zero = {0.f, 0.f, 0.f, 0.f};
#pragma unroll
  for (int mi = 0; mi < 4; ++mi)
#pragma unroll
    for (int ni = 0; ni < 8; ++ni) acc[mi][ni] = zero;

  u16* BWw = &BW[w * 8192];
  auto STAGE_B = [&](int t) {  // 8 gload16, wave-private slice (cols w*128..)
    u16* dst = BWw + (t & 1) * 4096;
#pragma unroll
    for (int q8 = 0; q8 < 8; ++q8)
      gload16(Bg2 + (long)q8 * 16 * 8192 + t * 32, dst + q8 * 512);
  };
  auto STAGE_A = [&](int t, int slot) {  // waves 0..3: row-group w
    gload16(Ag2 + (long)w * 16 * 8192 + t * 32, &AT[slot * 2048 + w * 512]);
  };

  // ---- prologue: A(0..3) slots 0..3; B(0),B(1). ----
  if (w < 4) { STAGE_A(0, 0); STAGE_A(1, 1); STAGE_A(2, 2); STAGE_A(3, 3); }
  STAGE_B(0); STAGE_B(1);
  VMCNT8();
  BAR();

  const int pko = (g4 ^ ((rl >> 1) & 3)) * 8;

#pragma unroll
  for (int j = 0; j < 16; ++j) {
#pragma unroll
    for (int ti = 0; ti < 2; ++ti) {
      const int t = 2 * j + ti;
      const int slot = t % 6;
      if (t >= 30) { VMCNT0(); } else { VMCNT8(); }  // own B(t) resident
      const u16* Ab_ = &AT[slot * 2048];
      const u16* Bb_ = BWw + (t & 1) * 4096;
      bf16x8 aF[4], bF[8];
#pragma unroll
      for (int mi = 0; mi < 4; ++mi)
        aF[mi] = *reinterpret_cast<const bf16x8*>(&Ab_[(mi * 16 + rl) * 32 + pko]);
#pragma unroll
      for (int ni = 0; ni < 8; ++ni)
        bF[ni] = *reinterpret_cast<const bf16x8*>(&Bb_[(ni * 16 + rl) * 32 + pko]);
      // reads retired -> safe to overwrite this wave's B(t) buffer; MFMA
      // then covers the stage issue (lookahead ~2 tiles).
      LGKM0();
      if (t + 2 < 32) STAGE_B(t + 2);
      if (ti == 1 && w < 4 && 2 * j + 4 < 32) {
        STAGE_A(2 * j + 4, (2 * j + 4) % 6);
        STAGE_A(2 * j + 5, (2 * j + 5) % 6);
      }
      SB0(); __builtin_amdgcn_s_setprio(1);
#pragma unroll
      for (int mi = 0; mi < 4; ++mi)
#pragma unroll
        for (int ni = 0; ni < 8; ++ni)
          acc[mi][ni] = __builtin_amdgcn_mfma_f32_16x16x32_bf16(
              aF[mi], bF[ni], acc[mi][ni], 0, 0, 0);
      __builtin_amdgcn_s_setprio(0); SB0();
    }
    // window end: prove A(2j+2),A(2j+3) retired (older than B(2j+2) in FIFO;
    // outstanding <= B(2j+2..3) 16 + A(2j+4..5) 2 + A(2j+2..3) -> keep 16).
    if (w < 4) { VMCNT16(); }
    BAR();
  }

  // ---- softmax epilogue (red overlays AT) ----
  float* RED = reinterpret_cast<float*>(&AT[0]);  // [2][64][8]
  const float* betap = p.beta + h * 8192 + n * 1024 + w * 128 + rl;
  float betv[8];
#pragma unroll
  for (int ni = 0; ni < 8; ++ni) betv[ni] = betap[ni * 16];

  float rmax[4][4];
#pragma unroll
  for (int mi = 0; mi < 4; ++mi)
#pragma unroll
    for (int j = 0; j < 4; ++j) {
      float m = -3.0e38f;
#pragma unroll
      for (int ni = 0; ni < 8; ++ni) {
        float v = (acc[mi][ni][j] + betv[ni]) * 0.03125f;
        acc[mi][ni][j] = v;
        m = fmaxf(m, v);
      }
      rmax[mi][j] = m;
    }
#pragma unroll
  for (int msk = 1; msk < 16; msk <<= 1)
#pragma unroll
    for (int mi = 0; mi < 4; ++mi)
#pragma unroll
      for (int j = 0; j < 4; ++j)
        rmax[mi][j] = fmaxf(rmax[mi][j], __shfl_xor(rmax[mi][j], msk));
  if (rl == 0) {
#pragma unroll
    for (int mi = 0; mi < 4; ++mi)
#pragma unroll
      for (int j = 0; j < 4; ++j)
        RED[(mi * 16 + g4 * 4 + j) * 8 + w] = rmax[mi][j];
  }
  __syncthreads();
  float gmax[4][4];
#pragma unroll
  for (int mi = 0; mi < 4; ++mi)
#pragma unroll
    for (int j = 0; j < 4; ++j) {
      const int row = mi * 16 + g4 * 4 + j;
      float4 x = *reinterpret_cast<const float4*>(&RED[row * 8]);
      float4 y = *reinterpret_cast<const float4*>(&RED[row * 8 + 4]);
      gmax[mi][j] = fmaxf(fmaxf(fmaxf(x.x, x.y), fmaxf(x.z, x.w)),
                          fmaxf(fmaxf(y.x, y.y), fmaxf(y.z, y.w)));
    }
  float rsum[4][4];
#pragma unroll
  for (int mi = 0; mi < 4; ++mi)
#pragma unroll
    for (int j = 0; j < 4; ++j) {
      float s = 0.f;
#pragma unroll
      for (int ni = 0; ni < 8; ++ni) {
        float e = __expf(acc[mi][ni][j] - gmax[mi][j]);
        acc[mi][ni][j] = e;
        s += e;
      }
      rsum[mi][j] = s;
    }
#pragma unroll
  for (int msk = 1; msk < 16; msk <<= 1)
#pragma unroll
    for (int mi = 0; mi < 4; ++mi)
#pragma unroll
      for (int j = 0; j < 4; ++j) rsum[mi][j] += __shfl_xor(rsum[mi][j], msk);
  __syncthreads();  // RED[0] reads done before overwriting with sums
  if (rl == 0) {
#pragma unroll
    for (int mi = 0; mi < 4; ++mi)
#pragma unroll
      for (int j = 0; j < 4; ++j)
        RED[512 + (mi * 16 + g4 * 4 + j) * 8 + w] = rsum[mi][j];
  }
  __syncthreads();
  float* attn_b = p.attn + ((long)h * 8 + n) * 1048576;
  u16* P_b = p.P + ((long)h * 8 + n) * 1048576;
#pragma unroll
  for (int mi = 0; mi < 4; ++mi)
#pragma unroll
    for (int j = 0; j < 4; ++j) {
      const int row = mi * 16 + g4 * 4 + j;
      float4 x = *reinterpret_cast<const float4*>(&RED[512 + row * 8]);
      float4 y = *reinterpret_cast<const float4*>(&RED[512 + row * 8 + 4]);
      const float inv =
          1.0f / (x.x + x.y + x.z + x.w + y.x + y.y + y.z + y.w);
      float* ar = attn_b + (long)(row0 + row) * 1024 + w * 128 + rl;
      u16* pr = P_b + (long)(row0 + row) * 1024 + w * 128 + rl;
#pragma unroll
      for (int ni = 0; ni < 8; ++ni) {
        float v = acc[mi][ni][j] * inv;
        ar[ni * 16] = v;
        pr[ni * 16] = f2bf(v);
      }
    }
}

// ============================================================================
extern "C" void kernel_launch(void* const* d_in, const int* in_sizes, int n_in,
                              void* d_out, int out_size, void* d_ws,
                              size_t ws_size, hipStream_t stream) {
  const float* query = (const float*)d_in[0];
  const float* key_  = (const float*)d_in[1];
  const float* value = (const float*)d_in[2];
  const float* Wqkv  = (const float*)d_in[3];
  const float* bqkv  = (const float*)d_in[4];
  const float* Wo    = (const float*)d_in[5];
  const float* bo    = (const float*)d_in[6];
  const float* Wout  = (const float*)d_in[7];
  const float* bout  = (const float*)d_in[8];

  float* out  = (float*)d_out;
  float* attn = out + LNE;  // (H,N,L,S) f32

  u16* ws = (u16*)d_ws;
  u16* qbf   = ws + OF_QBF;
  u16* kbf   = ws + OF_KBF;
  u16* valT  = ws + OF_VALT;
  u16* WqT_F = ws + OF_F;
  u16* WkT   = ws + OF_WKT;
  u16* WvT   = ws + OF_WVT;
  u16* WoT   = ws + OF_WOT;
  u16* Woutb = ws + OF_WOUTB;
  u16* Gt    = ws + OF_GT;
  u16* Bm    = ws + OF_BM;
  u16* Tbuf  = ws + OF_T;    // T, then U
  u16* Pbuf  = ws + OF_P;    // P, then split-K partials (f32)
  float* part = (float*)(ws + OF_P);
  float* Sf   = (float*)d_ws + OF_SMALL_F;
  float* beta  = Sf;            // 65536
  float* bv2   = Sf + 65536;    // 8192
  float* be2   = Sf + 73728;    // 1024
  float* bpart = Sf + 74752;    // 65536

  // ---- converts ----
  {
    Cvt3P p;
    p.s[0] = query; p.s[1] = key_; p.s[2] = Wout;
    p.d[0] = qbf;   p.d[1] = kbf;  p.d[2] = Woutb;
    k_cvt3<<<dim3(512, 3), 256, 0, stream>>>(p);
  }
  {
    Tp5P p;
    p.s[0] = Wqkv;           p.d[0] = WqT_F; p.sld[0] = 1024; p.szs[0] = 3145728; p.dzs[0] = MM;
    p.s[1] = Wqkv + 1048576; p.d[1] = WkT;   p.sld[1] = 1024; p.szs[1] = 3145728; p.dzs[1] = MM;
    p.s[2] = Wqkv + 2097152; p.d[2] = WvT;   p.sld[2] = 1024; p.szs[2] = 3145728; p.dzs[2] = MM;
    p.s[3] = Wo;             p.d[3] = WoT;   p.sld[3] = 1024; p.szs[3] = MM;      p.dzs[3] = MM;
    p.s[4] = value;          p.d[4] = valT;  p.sld[4] = 8192; p.szs[4] = 1024;    p.dzs[4] = MM;
    k_tp5<<<dim3(16, 16, 40), 256, 0, stream>>>(p);
  }
  // ---- beta precompute ----
  k_bvec<<<dim3(4, 8, 8), 256, 0, stream>>>(Wqkv, bqkv, bpart);
  k_redb<<<32, 256, 0, stream>>>(bpart, bv2);
  k_rowdot<<<2048, 256, 0, stream>>>(key_, bv2, beta);

  const dim3 blk(512);

  // ---- Gt = WkT·WqT^T  and  Bm = Woutb·WoT^T ----
  {
    GemmP g = {};
    g.A = WkT; g.lda = 1024; g.sAh = MM; g.sAn = 0;
    g.B = WqT_F; g.ldb = 1024; g.sBh = MM; g.sBn = 0;
    g.Cb = Gt; g.ldc = 1024; g.sCh = MM; g.sCn = 0;
    g.K = 1024; g.NB = 1; g.scale = 1.f;
    GemmP m = {};
    m.A = Woutb; m.lda = 8192; m.sAh = 1024; m.sAn = 0;
    m.B = WoT; m.ldb = 1024; m.sBh = MM; m.sBn = 0;
    m.Cb = Bm; m.ldc = 8192; m.sCh = 1024; m.sCn = 0;
    m.K = 1024; m.NB = 1; m.scale = 1.f;
    GemmP2 pp = {g, m, 8};
    k_gemm256_pair<0><<<dim3(4, 4, 16), blk, 0, stream>>>(pp);
  }
  k_be2<<<1024, 256, 0, stream>>>(Wout, bo, bout, bqkv, Bm, be2);
  // ---- T = qbf·Gt^T (z<64) and F = Bm·WvT^T (z>=64) ----
  {
    GemmP t = {};
    t.A = qbf; t.lda = 8192; t.sAh = 0; t.sAn = 1024;
    t.B = Gt; t.ldb = 1024; t.sBh = MM; t.sBn = 0;
    t.Cb = Tbuf; t.ldc = 8192; t.sCh = 8388608; t.sCn = 1024;
    t.K = 1024; t.NB = 8; t.scale = 1.f;
    GemmP f = {};
    f.A = Bm; f.lda = 8192; f.sAh = 1024; f.sAn = 0;
    f.B = WvT; f.ldb = 1024; f.sBh = MM; f.sBn = 0;
    f.Cb = WqT_F; f.ldc = 8192; f.sCh = 1024; f.sCn = 0;
    f.K = 1024; f.NB = 1; f.scale = 1.f;
    GemmP2 pp = {t, f, 64};
    k_gemm256_pair<0><<<dim3(4, 4, 72), blk, 0, stream>>>(pp);
  }
  // ---- FUSED scores+softmax -> attn f32 + P bf16 ----
  {
    FscP p = {Tbuf, kbf, beta, attn, Pbuf};
    k_fsc<<<dim3(16, 64), blk, 0, stream>>>(p);
  }
  // ---- U = P·valT^T (n-major batch chunking: bz = n*8 + h) ----
  {
    GemmP p = {};
    p.A = Pbuf; p.lda = 1024; p.sAh = 1048576; p.sAn = 8388608;
    p.B = valT; p.ldb = 1024; p.sBh = 1048576; p.sBn = 0;
    p.Cb = Tbuf; p.ldc = 65536; p.sCh = 8192; p.sCn = 1024;
    p.K = 1024; p.NB = 8; p.scale = 1.f;
    k_gemm256<0><<<dim3(4, 4, 64), blk, 0, stream>>>(p);
  }
  // ---- out partials split-K=2, L2-resident F panels ----
  {
    GemmP p = {};
    p.A = Tbuf; p.lda = 8192; p.sAh = 4096; p.sAn = 0;
    p.B = WqT_F; p.ldb = 8192; p.sBh = 4096; p.sBn = 0;
    p.Cf = part; p.ldc = 1024; p.sCh = 8388608; p.sCn = 0;
    p.K = 4096; p.NB = 1; p.scale = 1.f;
    k_gemm256_out<1><<<dim3(256), blk, 0, stream>>>(p);
  }
  k_combine<<<2048, 256, 0, stream>>>(part, part + 8388608, be2, out);
}

// Round 11
// 890.655 us; speedup vs baseline: 1.0429x; 1.0429x over previous
//
#include <hip/hip_runtime.h>
#include <stdint.h>

// ============================================================================
// CrossMultiHeadAttention (L=1024, N=8, E=1024, H=8) — round 11.
//  = round 10 with the out-GEMM decode REVERTED to round 9's swz_block
//  (round 10's pid%8=(bx,bz) mapping regressed ~35us: 4MB F panel == L2 size,
//  evicted by concurrent A streams -> no residency + worse A sharing).
//  fsc v7 kept (268us, marginal win, passing).
// ============================================================================

typedef unsigned short u16;
typedef unsigned int u32;
typedef __attribute__((ext_vector_type(8))) __bf16 bf16x8;
typedef __attribute__((ext_vector_type(4))) float f32x4;
typedef __attribute__((ext_vector_type(4))) u16 u16x4;

#define DEVFN static __device__ __forceinline__

static constexpr int LQ = 1024, NN = 8, EE = 1024, HH = 8, SS = 1024;
static constexpr long LNE = (long)LQ * NN * EE;   // 8,388,608
static constexpr long MM = 1048576;

// ws offsets (u16 elems)
static constexpr long OF_QBF   = 0;
static constexpr long OF_KBF   = 8388608;
static constexpr long OF_VALT  = 16777216;
static constexpr long OF_F     = 25165824;   // WqT first, later F
static constexpr long OF_WKT   = 33554432;
static constexpr long OF_WVT   = 41943040;
static constexpr long OF_WOT   = 50331648;
static constexpr long OF_WOUTB = 58720256;
static constexpr long OF_GT    = 67108864;
static constexpr long OF_BM    = 75497472;
static constexpr long OF_T     = 83886080;   // 67M u16: T, later U
static constexpr long OF_P     = 150994944;  // 67M u16: P, later 2 f32 partials
static constexpr long OF_SMALL_F = 109051904; // float index

DEVFN u16 f2bf(float x) {
  u32 u = __builtin_bit_cast(u32, x);
  u = (u + 0x7FFFu + ((u >> 16) & 1u)) >> 16;
  return (u16)u;
}
DEVFN float bf2f(u16 x) { return __builtin_bit_cast(float, (u32)x << 16); }

DEVFN void gload16(const u16* g, u16* l) {
  __builtin_amdgcn_global_load_lds(
      (const __attribute__((address_space(1))) void*)(uintptr_t)g,
      (__attribute__((address_space(3))) void*)(uintptr_t)l, 16, 0, 0);
}

#define BAR() asm volatile("s_barrier" ::: "memory")
#define VMCNT2() asm volatile("s_waitcnt vmcnt(2)" ::: "memory")
#define VMCNT0() asm volatile("s_waitcnt vmcnt(0)" ::: "memory")
#define VMCNT8() asm volatile("s_waitcnt vmcnt(8)" ::: "memory")
#define VMCNT16() asm volatile("s_waitcnt vmcnt(16)" ::: "memory")
#define LGKM0() asm volatile("s_waitcnt lgkmcnt(0)" ::: "memory")
#define SB0() __builtin_amdgcn_sched_barrier(0)

// ---------------- converts ----------------
struct Cvt3P { const float* s[3]; u16* d[3]; };
__global__ __launch_bounds__(256) void k_cvt3(Cvt3P p) {
  const int z = blockIdx.y;
  const float* s = p.s[z];
  u16* d = p.d[z];
  long i = (long)blockIdx.x * 256 + threadIdx.x;
  for (; i < 2097152; i += 131072) {
    float4 v = reinterpret_cast<const float4*>(s)[i];
    u16x4 o;
    o.x = f2bf(v.x); o.y = f2bf(v.y); o.z = f2bf(v.z); o.w = f2bf(v.w);
    reinterpret_cast<u16x4*>(d)[i] = o;
  }
}

struct Tp5P { const float* s[5]; u16* d[5]; int sld[5]; long szs[5]; long dzs[5]; };
__global__ __launch_bounds__(256) void k_tp5(Tp5P p) {
  const int cfg = blockIdx.z >> 3, zz = blockIdx.z & 7;
  const float* src = p.s[cfg] + (long)zz * p.szs[cfg];
  u16* dst = p.d[cfg] + (long)zz * p.dzs[cfg];
  const int sld = p.sld[cfg];
  __shared__ float t[64][65];
  const int r = threadIdx.x >> 4, c4 = (threadIdx.x & 15) * 4;
#pragma unroll
  for (int rr = 0; rr < 64; rr += 16) {
    float4 v = *reinterpret_cast<const float4*>(
        &src[(long)(blockIdx.y * 64 + r + rr) * sld + blockIdx.x * 64 + c4]);
    t[r + rr][c4] = v.x; t[r + rr][c4 + 1] = v.y;
    t[r + rr][c4 + 2] = v.z; t[r + rr][c4 + 3] = v.w;
  }
  __syncthreads();
#pragma unroll
  for (int rr = 0; rr < 64; rr += 16) {
    u16x4 o;
    o.x = f2bf(t[c4][r + rr]);     o.y = f2bf(t[c4 + 1][r + rr]);
    o.z = f2bf(t[c4 + 2][r + rr]); o.w = f2bf(t[c4 + 3][r + rr]);
    *reinterpret_cast<u16x4*>(
        &dst[(long)(blockIdx.x * 64 + r + rr) * 1024 + blockIdx.y * 64 + c4]) = o;
  }
}

// ---------------- beta vector: bvec_h[e] = sum_d Wk[h][d][e]*bq[h][d] -------
__global__ __launch_bounds__(256) void k_bvec(const float* __restrict__ Wqkv,
                                              const float* __restrict__ bqkv,
                                              float* __restrict__ bp) {
  const int ec = blockIdx.x, h = blockIdx.y, dc = blockIdx.z, t = threadIdx.x;
  const int e = ec * 256 + t;
  const float* wk = Wqkv + (long)h * 3145728 + 1048576;
  const float* bq = bqkv + h * 3072;
  float sb = 0.f;
  for (int dd = 0; dd < 128; ++dd) {
    const int d = dc * 128 + dd;
    sb += wk[(long)d * 1024 + e] * bq[d];
  }
  bp[dc * 8192 + h * 1024 + e] = sb;
}
__global__ __launch_bounds__(256) void k_redb(const float* __restrict__ bp,
                                              float* __restrict__ b) {
  const int i = blockIdx.x * 256 + threadIdx.x;
  float sb = 0.f;
#pragma unroll
  for (int dc = 0; dc < 8; ++dc) sb += bp[dc * 8192 + i];
  b[i] = sb;
}

// ---------------- beta[h,n,s] = key_row(s,n) · bvec_h -----------------------
__global__ __launch_bounds__(256) void k_rowdot(const float* __restrict__ X,
                                                const float* __restrict__ V,
                                                float* __restrict__ OUT) {
  const int wave = threadIdx.x >> 6, lane = threadIdx.x & 63;
  const int r = blockIdx.x * 4 + wave;  // row (s*8+n)
  const float4* xr = reinterpret_cast<const float4*>(X + (long)r * 1024);
  float acc[8];
#pragma unroll
  for (int h = 0; h < 8; ++h) acc[h] = 0.f;
#pragma unroll
  for (int it = 0; it < 4; ++it) {
    float4 q = xr[it * 64 + lane];
#pragma unroll
    for (int h = 0; h < 8; ++h) {
      float4 av = reinterpret_cast<const float4*>(V + h * 1024)[it * 64 + lane];
      acc[h] += q.x * av.x + q.y * av.y + q.z * av.z + q.w * av.w;
    }
  }
#pragma unroll
  for (int h = 0; h < 8; ++h)
#pragma unroll
    for (int o = 1; o < 64; o <<= 1) acc[h] += __shfl_xor(acc[h], o);
  if (lane == 0) {
    const int idx = r >> 3, n = r & 7;
#pragma unroll
    for (int h = 0; h < 8; ++h) OUT[h * 8192 + n * 1024 + idx] = acc[h];
  }
}

// ---------------- be2[e] = bout + Wout[e,:]·bo + Bm[e,:]·bv -----------------
__global__ __launch_bounds__(256) void k_be2(const float* __restrict__ Wout,
                                             const float* __restrict__ bo,
                                             const float* __restrict__ bout,
                                             const float* __restrict__ bqkv,
                                             const u16* __restrict__ Bm,
                                             float* __restrict__ be2) {
  const int e = blockIdx.x, t = threadIdx.x;
  float s = 0.f;
  for (int i = t; i < 8192; i += 256) {
    s += Wout[(long)e * 8192 + i] * bo[i];
    const int h = i >> 10, d = i & 1023;
    s += bf2f(Bm[(long)e * 8192 + i]) * bqkv[h * 3072 + 2048 + d];
  }
#pragma unroll
  for (int o = 1; o < 64; o <<= 1) s += __shfl_xor(s, o);
  __shared__ float ps[4];
  if ((t & 63) == 0) ps[t >> 6] = s;
  __syncthreads();
  if (t == 0) be2[e] = bout[e] + ps[0] + ps[1] + ps[2] + ps[3];
}

// ---------------- out = p0 + p1 + be2 ---------------------------------------
__global__ __launch_bounds__(256) void k_combine(const float* __restrict__ p0,
                                                 const float* __restrict__ p1,
                                                 const float* __restrict__ be,
                                                 float* __restrict__ out) {
  long i = (long)blockIdx.x * 256 + threadIdx.x;
  const long st = (long)gridDim.x * 256;
  for (; i < 2097152; i += st) {
    float4 a = reinterpret_cast<const float4*>(p0)[i];
    float4 b = reinterpret_cast<const float4*>(p1)[i];
    float4 c = reinterpret_cast<const float4*>(be)[i & 255];
    float4 o = {a.x + b.x + c.x, a.y + b.y + c.y, a.z + b.z + c.z, a.w + b.w + c.w};
    reinterpret_cast<float4*>(out)[i] = o;
  }
}

// ---------------- generic 256x256 8-phase B^T GEMM --------------------------
struct GemmP {
  const u16* A; const u16* B;
  float* Cf; u16* Cb;
  int lda, ldb, ldc, K, NB;
  long sAh, sAn, sBh, sBn, sCh, sCn;
  float scale;
};
struct GemmP2 { GemmP p0, p1; int split; };

template <int M0, int N0>
DEVFN void quad(f32x4 (&acc)[8][4], bf16x8 (&a)[4][2], bf16x8 (&b)[4][2]) {
#pragma unroll
  for (int mi = 0; mi < 4; ++mi)
#pragma unroll
    for (int ni = 0; ni < 2; ++ni) {
      acc[M0 + mi][N0 + ni] = __builtin_amdgcn_mfma_f32_16x16x32_bf16(
          a[mi][0], b[N0 + ni][0], acc[M0 + mi][N0 + ni], 0, 0, 0);
      acc[M0 + mi][N0 + ni] = __builtin_amdgcn_mfma_f32_16x16x32_bf16(
          a[mi][1], b[N0 + ni][1], acc[M0 + mi][N0 + ni], 0, 0, 0);
    }
}

DEVFN void swz_block(int& bx, int& by, int& bz) {
  long lid = blockIdx.x + (long)gridDim.x * (blockIdx.y + (long)gridDim.y * blockIdx.z);
  const long nwg = (long)gridDim.x * gridDim.y * gridDim.z;
  long s = (nwg % 8 == 0) ? ((lid % 8) * (nwg / 8) + lid / 8) : lid;
  bx = (int)(s % gridDim.x);
  long r2 = s / gridDim.x;
  by = (int)(r2 % gridDim.y);
  bz = (int)(r2 / gridDim.y);
}

template <int OUT_F32>
DEVFN void gemm_body(const GemmP& p, int bx, int by, int bz) {
  const int h = bz / p.NB, n = bz % p.NB;
  const u16* Ab = p.A + (long)h * p.sAh + (long)n * p.sAn;
  const u16* Bb = p.B + (long)h * p.sBh + (long)n * p.sBn;
  const long coff = (long)h * p.sCh + (long)n * p.sCn;
  const int row0 = by * 256;
  const int col0 = bx * 256;

  __shared__ u16 LDSU[65536];  // 128 KiB

  const int tid = threadIdx.x;
  const int wave = tid >> 6, lane = tid & 63;
  const int wr = wave >> 2, wc = wave & 3;
  const int NT = p.K >> 6;

  f32x4 acc[8][4];
  const f32x4 zero = {0.f, 0.f, 0.f, 0.f};
#pragma unroll
  for (int i = 0; i < 8; ++i)
#pragma unroll
    for (int j = 0; j < 4; ++j) acc[i][j] = zero;

  const int swc = ((lane & 7) ^ ((lane >> 3) & 7)) * 8;
  const u16* Ag = Ab + (long)(row0 + wave * 16 + (lane >> 3)) * p.lda + swc;
  const u16* Bg = Bb + (long)(col0 + wave * 16 + (lane >> 3)) * p.ldb + swc;

  auto STAGE = [&](int hh) {
    const int kt = hh >> 2;
    if (kt < NT) {
      const int pt = hh & 3;
      const int hf = pt >> 1;
      u16* l = &LDSU[((pt & 1) ? 32768 : 0) + (kt & 1) * 16384 + hf * 8192 + wave * 1024];
      const int ld = (pt & 1) ? p.ldb : p.lda;
      const u16* g = ((pt & 1) ? Bg : Ag) + (long)hf * 128 * ld + kt * 64;
      gload16(g, l);
      gload16(g + 8L * ld, l + 512);
    }
  };

  STAGE(0); STAGE(1); STAGE(2); STAGE(3); STAGE(4);
  VMCNT2();
  BAR();

  const int rA = lane & 15;
  const int c0 = (((lane >> 4)) ^ (lane & 7)) * 8;
  const int c1 = ((4 + (lane >> 4)) ^ (lane & 7)) * 8;

  bf16x8 a[4][2], b[4][2];

  for (int t = 0; t < NT; ++t) {
    const int db = (t & 1) * 16384;
    const u16* Ar = &LDSU[db + wr * 8192 + rA * 64];
    const u16* Br = &LDSU[32768 + db + (wc >> 1) * 8192 + ((wc & 1) * 64 + rA) * 64];

#pragma unroll
    for (int mi = 0; mi < 4; ++mi) {
      a[mi][0] = *reinterpret_cast<const bf16x8*>(&Ar[mi * 1024 + c0]);
      a[mi][1] = *reinterpret_cast<const bf16x8*>(&Ar[mi * 1024 + c1]);
    }
#pragma unroll
    for (int ni = 0; ni < 2; ++ni) {
      b[ni][0] = *reinterpret_cast<const bf16x8*>(&Br[ni * 1024 + c0]);
      b[ni][1] = *reinterpret_cast<const bf16x8*>(&Br[ni * 1024 + c1]);
    }
    STAGE(4 * t + 5);
    BAR();
    SB0(); __builtin_amdgcn_s_setprio(1);
    quad<0, 0>(acc, a, b);
    __builtin_amdgcn_s_setprio(0); SB0();
    BAR();

#pragma unroll
    for (int ni = 2; ni < 4; ++ni) {
      b[ni][0] = *reinterpret_cast<const bf16x8*>(&Br[ni * 1024 + c0]);
      b[ni][1] = *reinterpret_cast<const bf16x8*>(&Br[ni * 1024 + c1]);
    }
    STAGE(4 * t + 6);
    BAR();
    SB0(); __builtin_amdgcn_s_setprio(1);
    quad<0, 2>(acc, a, b);
    __builtin_amdgcn_s_setprio(0); SB0();
    BAR();

#pragma unroll
    for (int mi = 0; mi < 4; ++mi) {
      a[mi][0] = *reinterpret_cast<const bf16x8*>(&Ar[(4 + mi) * 1024 + c0]);
      a[mi][1] = *reinterpret_cast<const bf16x8*>(&Ar[(4 + mi) * 1024 + c1]);
    }
    STAGE(4 * t + 7);
    BAR();
    SB0(); __builtin_amdgcn_s_setprio(1);
    quad<4, 0>(acc, a, b);
    __builtin_amdgcn_s_setprio(0); SB0();
    BAR();

    STAGE(4 * t + 8);
    if (t < NT - 2) { VMCNT2(); }
    else if (t == NT - 2) { VMCNT0(); }
    BAR();
    SB0(); __builtin_amdgcn_s_setprio(1);
    quad<4, 2>(acc, a, b);
    __builtin_amdgcn_s_setprio(0); SB0();
    BAR();
  }

  const int crow = (lane >> 4) * 4;
  const int ccol = lane & 15;
#pragma unroll
  for (int mi = 0; mi < 8; ++mi) {
#pragma unroll
    for (int j = 0; j < 4; ++j) {
      const int grow = row0 + wr * 128 + mi * 16 + crow + j;
#pragma unroll
      for (int ni = 0; ni < 4; ++ni) {
        const int gcol = col0 + wc * 64 + ni * 16 + ccol;
        float v = acc[mi][ni][j] * p.scale;
        if constexpr (OUT_F32)
          p.Cf[coff + (long)grow * p.ldc + gcol] = v;
        else
          p.Cb[coff + (long)grow * p.ldc + gcol] = f2bf(v);
      }
    }
  }
}

template <int OUT_F32>
__global__ __launch_bounds__(512, 2) void k_gemm256(GemmP p) {
  int bx, by, bz;
  swz_block(bx, by, bz);
  gemm_body<OUT_F32>(p, bx, by, bz);
}
template <int OUT_F32>
__global__ __launch_bounds__(512, 2) void k_gemm256_pair(GemmP2 pp) {
  int bx, by, bz;
  swz_block(bx, by, bz);
  if (bz < pp.split) gemm_body<OUT_F32>(pp.p0, bx, by, bz);
  else gemm_body<OUT_F32>(pp.p1, bx, by, bz - pp.split);
}

// ---------------- FUSED scores+softmax v7 (k_fsc) ---------------------------
struct FscP {
  const u16* T; const u16* K; const float* beta;
  float* attn; u16* P;
};
__global__ __launch_bounds__(512, 2) void k_fsc(FscP p) {
  const int lid = blockIdx.x + 16 * blockIdx.y;  // grid (16,64) -> 1024
  const int n = lid & 7;                          // XCD-local batch
  const int rest = lid >> 3;                      // 0..127
  const int bx = rest & 15;
  const int h = rest >> 4;
  const int row0 = bx * 64;

  __shared__ u16 BW[65536];   // 128 KB: w*8192 + buf*4096 + c*32 + pk*8
  __shared__ u16 AT[12288];   // 24 KB: slot*2048 + r*32 + pk*8  (slot = t%6)

  const int tid = threadIdx.x;
  const int w = tid >> 6, lane = tid & 63;
  const int rl = lane & 15, g4 = lane >> 4;

  const u16* Abase = p.T + (long)h * 8388608 + n * 1024 + (long)row0 * 8192;
  const int ksw = ((lane & 3) ^ ((lane >> 3) & 3)) * 8;
  const u16* Ag2 = Abase + (long)(lane >> 2) * 8192 + ksw;             // row
  const u16* Bg2 = p.K + n * 1024 + (long)(w * 128 + (lane >> 2)) * 8192 + ksw;

  f32x4 acc[4][8];
  const f32x4 zero = {0.f, 0.f, 0.f, 0.f};
#pragma unroll
  for (int mi = 0; mi < 4; ++mi)
#pragma unroll
    for (int ni = 0; ni < 8; ++ni) acc[mi][ni] = zero;

  u16* BWw = &BW[w * 8192];
  auto STAGE_B = [&](int t) {  // 8 gload16, wave-private slice (cols w*128..)
    u16* dst = BWw + (t & 1) * 4096;
#pragma unroll
    for (int q8 = 0; q8 < 8; ++q8)
      gload16(Bg2 + (long)q8 * 16 * 8192 + t * 32, dst + q8 * 512);
  };
  auto STAGE_A = [&](int t, int slot) {  // waves 0..3: row-group w
    gload16(Ag2 + (long)w * 16 * 8192 + t * 32, &AT[slot * 2048 + w * 512]);
  };

  // ---- prologue: A(0..3) slots 0..3; B(0),B(1). ----
  if (w < 4) { STAGE_A(0, 0); STAGE_A(1, 1); STAGE_A(2, 2); STAGE_A(3, 3); }
  STAGE_B(0); STAGE_B(1);
  VMCNT8();
  BAR();

  const int pko = (g4 ^ ((rl >> 1) & 3)) * 8;

#pragma unroll
  for (int j = 0; j < 16; ++j) {
#pragma unroll
    for (int ti = 0; ti < 2; ++ti) {
      const int t = 2 * j + ti;
      const int slot = t % 6;
      if (t >= 30) { VMCNT0(); } else { VMCNT8(); }  // own B(t) resident
      const u16* Ab_ = &AT[slot * 2048];
      const u16* Bb_ = BWw + (t & 1) * 4096;
      bf16x8 aF[4], bF[8];
#pragma unroll
      for (int mi = 0; mi < 4; ++mi)
        aF[mi] = *reinterpret_cast<const bf16x8*>(&Ab_[(mi * 16 + rl) * 32 + pko]);
#pragma unroll
      for (int ni = 0; ni < 8; ++ni)
        bF[ni] = *reinterpret_cast<const bf16x8*>(&Bb_[(ni * 16 + rl) * 32 + pko]);
      LGKM0();
      if (t + 2 < 32) STAGE_B(t + 2);
      if (ti == 1 && w < 4 && 2 * j + 4 < 32) {
        STAGE_A(2 * j + 4, (2 * j + 4) % 6);
        STAGE_A(2 * j + 5, (2 * j + 5) % 6);
      }
      SB0(); __builtin_amdgcn_s_setprio(1);
#pragma unroll
      for (int mi = 0; mi < 4; ++mi)
#pragma unroll
        for (int ni = 0; ni < 8; ++ni)
          acc[mi][ni] = __builtin_amdgcn_mfma_f32_16x16x32_bf16(
              aF[mi], bF[ni], acc[mi][ni], 0, 0, 0);
      __builtin_amdgcn_s_setprio(0); SB0();
    }
    if (w < 4) { VMCNT16(); }
    BAR();
  }

  // ---- softmax epilogue (red overlays AT) ----
  float* RED = reinterpret_cast<float*>(&AT[0]);  // [2][64][8]
  const float* betap = p.beta + h * 8192 + n * 1024 + w * 128 + rl;
  float betv[8];
#pragma unroll
  for (int ni = 0; ni < 8; ++ni) betv[ni] = betap[ni * 16];

  float rmax[4][4];
#pragma unroll
  for (int mi = 0; mi < 4; ++mi)
#pragma unroll
    for (int j = 0; j < 4; ++j) {
      float m = -3.0e38f;
#pragma unroll
      for (int ni = 0; ni < 8; ++ni) {
        float v = (acc[mi][ni][j] + betv[ni]) * 0.03125f;
        acc[mi][ni][j] = v;
        m = fmaxf(m, v);
      }
      rmax[mi][j] = m;
    }
#pragma unroll
  for (int msk = 1; msk < 16; msk <<= 1)
#pragma unroll
    for (int mi = 0; mi < 4; ++mi)
#pragma unroll
      for (int j = 0; j < 4; ++j)
        rmax[mi][j] = fmaxf(rmax[mi][j], __shfl_xor(rmax[mi][j], msk));
  if (rl == 0) {
#pragma unroll
    for (int mi = 0; mi < 4; ++mi)
#pragma unroll
      for (int j = 0; j < 4; ++j)
        RED[(mi * 16 + g4 * 4 + j) * 8 + w] = rmax[mi][j];
  }
  __syncthreads();
  float gmax[4][4];
#pragma unroll
  for (int mi = 0; mi < 4; ++mi)
#pragma unroll
    for (int j = 0; j < 4; ++j) {
      const int row = mi * 16 + g4 * 4 + j;
      float4 x = *reinterpret_cast<const float4*>(&RED[row * 8]);
      float4 y = *reinterpret_cast<const float4*>(&RED[row * 8 + 4]);
      gmax[mi][j] = fmaxf(fmaxf(fmaxf(x.x, x.y), fmaxf(x.z, x.w)),
                          fmaxf(fmaxf(y.x, y.y), fmaxf(y.z, y.w)));
    }
  float rsum[4][4];
#pragma unroll
  for (int mi = 0; mi < 4; ++mi)
#pragma unroll
    for (int j = 0; j < 4; ++j) {
      float s = 0.f;
#pragma unroll
      for (int ni = 0; ni < 8; ++ni) {
        float e = __expf(acc[mi][ni][j] - gmax[mi][j]);
        acc[mi][ni][j] = e;
        s += e;
      }
      rsum[mi][j] = s;
    }
#pragma unroll
  for (int msk = 1; msk < 16; msk <<= 1)
#pragma unroll
    for (int mi = 0; mi < 4; ++mi)
#pragma unroll
      for (int j = 0; j < 4; ++j) rsum[mi][j] += __shfl_xor(rsum[mi][j], msk);
  __syncthreads();  // RED[0] reads done before overwriting with sums
  if (rl == 0) {
#pragma unroll
    for (int mi = 0; mi < 4; ++mi)
#pragma unroll
      for (int j = 0; j < 4; ++j)
        RED[512 + (mi * 16 + g4 * 4 + j) * 8 + w] = rsum[mi][j];
  }
  __syncthreads();
  float* attn_b = p.attn + ((long)h * 8 + n) * 1048576;
  u16* P_b = p.P + ((long)h * 8 + n) * 1048576;
#pragma unroll
  for (int mi = 0; mi < 4; ++mi)
#pragma unroll
    for (int j = 0; j < 4; ++j) {
      const int row = mi * 16 + g4 * 4 + j;
      float4 x = *reinterpret_cast<const float4*>(&RED[512 + row * 8]);
      float4 y = *reinterpret_cast<const float4*>(&RED[512 + row * 8 + 4]);
      const float inv =
          1.0f / (x.x + x.y + x.z + x.w + y.x + y.y + y.z + y.w);
      float* ar = attn_b + (long)(row0 + row) * 1024 + w * 128 + rl;
      u16* pr = P_b + (long)(row0 + row) * 1024 + w * 128 + rl;
#pragma unroll
      for (int ni = 0; ni < 8; ++ni) {
        float v = acc[mi][ni][j] * inv;
        ar[ni * 16] = v;
        pr[ni * 16] = f2bf(v);
      }
    }
}

// ============================================================================
extern "C" void kernel_launch(void* const* d_in, const int* in_sizes, int n_in,
                              void* d_out, int out_size, void* d_ws,
                              size_t ws_size, hipStream_t stream) {
  const float* query = (const float*)d_in[0];
  const float* key_  = (const float*)d_in[1];
  const float* value = (const float*)d_in[2];
  const float* Wqkv  = (const float*)d_in[3];
  const float* bqkv  = (const float*)d_in[4];
  const float* Wo    = (const float*)d_in[5];
  const float* bo    = (const float*)d_in[6];
  const float* Wout  = (const float*)d_in[7];
  const float* bout  = (const float*)d_in[8];

  float* out  = (float*)d_out;
  float* attn = out + LNE;  // (H,N,L,S) f32

  u16* ws = (u16*)d_ws;
  u16* qbf   = ws + OF_QBF;
  u16* kbf   = ws + OF_KBF;
  u16* valT  = ws + OF_VALT;
  u16* WqT_F = ws + OF_F;
  u16* WkT   = ws + OF_WKT;
  u16* WvT   = ws + OF_WVT;
  u16* WoT   = ws + OF_WOT;
  u16* Woutb = ws + OF_WOUTB;
  u16* Gt    = ws + OF_GT;
  u16* Bm    = ws + OF_BM;
  u16* Tbuf  = ws + OF_T;    // T, then U
  u16* Pbuf  = ws + OF_P;    // P, then split-K partials (f32)
  float* part = (float*)(ws + OF_P);
  float* Sf   = (float*)d_ws + OF_SMALL_F;
  float* beta  = Sf;            // 65536
  float* bv2   = Sf + 65536;    // 8192
  float* be2   = Sf + 73728;    // 1024
  float* bpart = Sf + 74752;    // 65536

  // ---- converts ----
  {
    Cvt3P p;
    p.s[0] = query; p.s[1] = key_; p.s[2] = Wout;
    p.d[0] = qbf;   p.d[1] = kbf;  p.d[2] = Woutb;
    k_cvt3<<<dim3(512, 3), 256, 0, stream>>>(p);
  }
  {
    Tp5P p;
    p.s[0] = Wqkv;           p.d[0] = WqT_F; p.sld[0] = 1024; p.szs[0] = 3145728; p.dzs[0] = MM;
    p.s[1] = Wqkv + 1048576; p.d[1] = WkT;   p.sld[1] = 1024; p.szs[1] = 3145728; p.dzs[1] = MM;
    p.s[2] = Wqkv + 2097152; p.d[2] = WvT;   p.sld[2] = 1024; p.szs[2] = 3145728; p.dzs[2] = MM;
    p.s[3] = Wo;             p.d[3] = WoT;   p.sld[3] = 1024; p.szs[3] = MM;      p.dzs[3] = MM;
    p.s[4] = value;          p.d[4] = valT;  p.sld[4] = 8192; p.szs[4] = 1024;    p.dzs[4] = MM;
    k_tp5<<<dim3(16, 16, 40), 256, 0, stream>>>(p);
  }
  // ---- beta precompute ----
  k_bvec<<<dim3(4, 8, 8), 256, 0, stream>>>(Wqkv, bqkv, bpart);
  k_redb<<<32, 256, 0, stream>>>(bpart, bv2);
  k_rowdot<<<2048, 256, 0, stream>>>(key_, bv2, beta);

  const dim3 blk(512);

  // ---- Gt = WkT·WqT^T  and  Bm = Woutb·WoT^T ----
  {
    GemmP g = {};
    g.A = WkT; g.lda = 1024; g.sAh = MM; g.sAn = 0;
    g.B = WqT_F; g.ldb = 1024; g.sBh = MM; g.sBn = 0;
    g.Cb = Gt; g.ldc = 1024; g.sCh = MM; g.sCn = 0;
    g.K = 1024; g.NB = 1; g.scale = 1.f;
    GemmP m = {};
    m.A = Woutb; m.lda = 8192; m.sAh = 1024; m.sAn = 0;
    m.B = WoT; m.ldb = 1024; m.sBh = MM; m.sBn = 0;
    m.Cb = Bm; m.ldc = 8192; m.sCh = 1024; m.sCn = 0;
    m.K = 1024; m.NB = 1; m.scale = 1.f;
    GemmP2 pp = {g, m, 8};
    k_gemm256_pair<0><<<dim3(4, 4, 16), blk, 0, stream>>>(pp);
  }
  k_be2<<<1024, 256, 0, stream>>>(Wout, bo, bout, bqkv, Bm, be2);
  // ---- T = qbf·Gt^T (z<64) and F = Bm·WvT^T (z>=64) ----
  {
    GemmP t = {};
    t.A = qbf; t.lda = 8192; t.sAh = 0; t.sAn = 1024;
    t.B = Gt; t.ldb = 1024; t.sBh = MM; t.sBn = 0;
    t.Cb = Tbuf; t.ldc = 8192; t.sCh = 8388608; t.sCn = 1024;
    t.K = 1024; t.NB = 8; t.scale = 1.f;
    GemmP f = {};
    f.A = Bm; f.lda = 8192; f.sAh = 1024; f.sAn = 0;
    f.B = WvT; f.ldb = 1024; f.sBh = MM; f.sBn = 0;
    f.Cb = WqT_F; f.ldc = 8192; f.sCh = 1024; f.sCn = 0;
    f.K = 1024; f.NB = 1; f.scale = 1.f;
    GemmP2 pp = {t, f, 64};
    k_gemm256_pair<0><<<dim3(4, 4, 72), blk, 0, stream>>>(pp);
  }
  // ---- FUSED scores+softmax -> attn f32 + P bf16 ----
  {
    FscP p = {Tbuf, kbf, beta, attn, Pbuf};
    k_fsc<<<dim3(16, 64), blk, 0, stream>>>(p);
  }
  // ---- U = P·valT^T (n-major batch chunking: bz = n*8 + h) ----
  {
    GemmP p = {};
    p.A = Pbuf; p.lda = 1024; p.sAh = 1048576; p.sAn = 8388608;
    p.B = valT; p.ldb = 1024; p.sBh = 1048576; p.sBn = 0;
    p.Cb = Tbuf; p.ldc = 65536; p.sCh = 8192; p.sCn = 1024;
    p.K = 1024; p.NB = 8; p.scale = 1.f;
    k_gemm256<0><<<dim3(4, 4, 64), blk, 0, stream>>>(p);
  }
  // ---- out partials split-K=2 (round-9 swz_block decode) ----
  {
    GemmP p = {};
    p.A = Tbuf; p.lda = 8192; p.sAh = 4096; p.sAn = 0;
    p.B = WqT_F; p.ldb = 8192; p.sBh = 4096; p.sBn = 0;
    p.Cf = part; p.ldc = 1024; p.sCh = 8388608; p.sCn = 0;
    p.K = 4096; p.NB = 1; p.scale = 1.f;
    k_gemm256<1><<<dim3(4, 32, 2), blk, 0, stream>>>(p);
  }
  k_combine<<<2048, 256, 0, stream>>>(part, part + 8388608, be2, out);
}